// Round 1
// baseline (588.455 us; speedup 1.0000x reference)
//
#include <hip/hip_runtime.h>

// Problem constants (fixed shapes from setup_inputs)
constexpr int B = 4, C = 128, H = 512, W = 512, N = 500;
constexpr float PC0   = -59.9f;   // PC_RANGE[0] == PC_RANGE[1]
constexpr float SPAN  = 119.8f;   // PC_RANGE[3]-PC_RANGE[0] == PC_RANGE[4]-PC_RANGE[1]
constexpr float INV_TEMP = 10.0f; // 1 / 0.1
constexpr float LOSS_SCALE = 0.01f;

// ---------------------------------------------------------------------------
// Kernel 1: gather feats[i][c] = sf[B-1, c, cy[i], cx[i]], double-normalize,
// write f (N x 128) to workspace.  One block per box, 128 threads (1/channel).
// ---------------------------------------------------------------------------
__global__ void gather_norm_kernel(const float* __restrict__ sf,
                                   const float* __restrict__ gt,
                                   float* __restrict__ f) {
    const int i = blockIdx.x;   // box index
    const int c = threadIdx.x;  // channel (128 threads)

    // box (x, y) from last batch; gt_boxes is (B, N, 8)
    const float x = gt[((size_t)(B - 1) * N + i) * 8 + 0];
    const float y = gt[((size_t)(B - 1) * N + i) * 8 + 1];

    int cx = (int)((x - PC0) / SPAN * (float)W);
    cx = min(max(cx, 0), W - 1);
    int cy = (int)((y - PC0) / SPAN * (float)H);
    cy = min(max(cy, 0), H - 1);

    const float v = sf[(size_t)(B - 1) * C * H * W +
                       (size_t)c * H * W + (size_t)cy * W + (size_t)cx];

    __shared__ float red[128];
    red[c] = v * v;
    __syncthreads();
    for (int s = 64; s > 0; s >>= 1) {
        if (c < s) red[c] += red[c + s];
        __syncthreads();
    }
    const float n1 = fmaxf(sqrtf(red[0]), 1e-12f);
    __syncthreads();

    const float v1 = v / n1;
    red[c] = v1 * v1;
    __syncthreads();
    for (int s = 64; s > 0; s >>= 1) {
        if (c < s) red[c] += red[c + s];
        __syncthreads();
    }
    const float n2 = fmaxf(sqrtf(red[0]), 1e-8f);

    f[(size_t)i * 128 + c] = v1 / n2;
}

// ---------------------------------------------------------------------------
// Kernel 2: per-row loss_i = logsumexp_j(sim[i,j]) - sim[i, label_i].
// One block per row i, 256 threads; each thread handles j = t and j = t+256.
// f is 256 KB -> stays L2 resident across the 500 blocks.
// ---------------------------------------------------------------------------
__global__ void row_loss_kernel(const float* __restrict__ f,
                                const int* __restrict__ slab,
                                const int* __restrict__ dlab,
                                const int* __restrict__ ns_ptr,
                                float* __restrict__ row_loss) {
    const int i = blockIdx.x;
    const int t = threadIdx.x;  // 256 threads
    const int Ns = ns_ptr[0];

    __shared__ float fi[128];
    if (t < 128) fi[t] = f[(size_t)i * 128 + t];
    __shared__ float sh_slabel;
    __syncthreads();

    const int label = (i < Ns) ? slab[i] : dlab[i - Ns];

    const float4* fi4 = (const float4*)fi;
    float sv[2];
    const int jv[2] = { t, t + 256 };

    #pragma unroll
    for (int k = 0; k < 2; ++k) {
        const int j = jv[k];
        if (j < N) {
            const float4* fj = (const float4*)(f + (size_t)j * 128);
            float acc = 0.f;
            #pragma unroll
            for (int c = 0; c < 32; ++c) {
                const float4 a = fi4[c];
                const float4 b = fj[c];
                acc += a.x * b.x + a.y * b.y + a.z * b.z + a.w * b.w;
            }
            acc *= INV_TEMP;
            if (j == label) sh_slabel = acc;  // exactly one writer per block
            sv[k] = acc;
        } else {
            sv[k] = -1e30f;
        }
    }

    __shared__ float red[256];
    // block max
    red[t] = fmaxf(sv[0], sv[1]);
    __syncthreads();
    for (int s = 128; s > 0; s >>= 1) {
        if (t < s) red[t] = fmaxf(red[t], red[t + s]);
        __syncthreads();
    }
    const float mx = red[0];
    __syncthreads();

    // block sum of exp(s - mx)
    float e = 0.f;
    if (jv[0] < N) e += expf(sv[0] - mx);
    if (jv[1] < N) e += expf(sv[1] - mx);
    red[t] = e;
    __syncthreads();
    for (int s = 128; s > 0; s >>= 1) {
        if (t < s) red[t] += red[t + s];
        __syncthreads();
    }

    if (t == 0) {
        const float lse = mx + logf(red[0]);
        row_loss[i] = lse - sh_slabel;
    }
}

// ---------------------------------------------------------------------------
// Kernel 3: deterministic final reduce of 500 row losses -> scalar loss.
// ---------------------------------------------------------------------------
__global__ void final_reduce_kernel(const float* __restrict__ row_loss,
                                    float* __restrict__ out) {
    const int t = threadIdx.x;  // 256
    float a = 0.f;
    for (int j = t; j < N; j += 256) a += row_loss[j];
    __shared__ float red[256];
    red[t] = a;
    __syncthreads();
    for (int s = 128; s > 0; s >>= 1) {
        if (t < s) red[t] += red[t + s];
        __syncthreads();
    }
    if (t == 0) out[0] = red[0] * (LOSS_SCALE / (float)N);
}

extern "C" void kernel_launch(void* const* d_in, const int* in_sizes, int n_in,
                              void* d_out, int out_size, void* d_ws, size_t ws_size,
                              hipStream_t stream) {
    const float* sf   = (const float*)d_in[0];  // (4,128,512,512) f32
    const float* gt   = (const float*)d_in[1];  // (4,500,8) f32
    const int*   slab = (const int*)d_in[2];    // (250,) i32
    const int*   dlab = (const int*)d_in[3];    // (250,) i32
    const int*   nsp  = (const int*)d_in[4];    // scalar 250

    float* f        = (float*)d_ws;             // N*128 floats = 256 KB
    float* row_loss = f + (size_t)N * 128;      // N floats

    gather_norm_kernel<<<N, 128, 0, stream>>>(sf, gt, f);
    row_loss_kernel<<<N, 256, 0, stream>>>(f, slab, dlab, nsp, row_loss);
    final_reduce_kernel<<<1, 256, 0, stream>>>(row_loss, (float*)d_out);
}

// Round 2
// 582.854 us; speedup vs baseline: 1.0096x; 1.0096x over previous
//
#include <hip/hip_runtime.h>

// Problem constants (fixed shapes from setup_inputs)
constexpr int B = 4, C = 128, H = 512, W = 512, N = 500;
constexpr float PC0   = -59.9f;   // PC_RANGE[0] == PC_RANGE[1]
constexpr float SPAN  = 119.8f;   // PC_RANGE[3]-PC_RANGE[0] == PC_RANGE[4]-PC_RANGE[1]
constexpr float INV_TEMP = 10.0f; // 1 / 0.1
constexpr float LOSS_SCALE = 0.01f;

__device__ __forceinline__ float wave_reduce_sum(float v) {
    #pragma unroll
    for (int m = 1; m < 64; m <<= 1) v += __shfl_xor(v, m, 64);
    return v;
}
__device__ __forceinline__ float wave_reduce_max(float v) {
    #pragma unroll
    for (int m = 1; m < 64; m <<= 1) v = fmaxf(v, __shfl_xor(v, m, 64));
    return v;
}

// ---------------------------------------------------------------------------
// Kernel 1: one WAVE per box (zero barriers). 125 blocks x 256 threads.
// Lane l handles channels 2l, 2l+1; shuffle reductions for both norm passes;
// coalesced float2 store of the normalized row.
// ---------------------------------------------------------------------------
__global__ __launch_bounds__(256) void gather_norm_kernel(
        const float* __restrict__ sf,
        const float* __restrict__ gt,
        float* __restrict__ f) {
    const int wave = threadIdx.x >> 6;
    const int lane = threadIdx.x & 63;
    const int i = blockIdx.x * 4 + wave;   // box index, 125*4 == 500 exact

    const float x = gt[((size_t)(B - 1) * N + i) * 8 + 0];
    const float y = gt[((size_t)(B - 1) * N + i) * 8 + 1];

    int cx = (int)((x - PC0) / SPAN * (float)W);
    cx = min(max(cx, 0), W - 1);
    int cy = (int)((y - PC0) / SPAN * (float)H);
    cy = min(max(cy, 0), H - 1);

    const float* base = sf + (size_t)(B - 1) * C * H * W + (size_t)cy * W + cx;
    float v0 = base[(size_t)(2 * lane)     * (H * W)];
    float v1 = base[(size_t)(2 * lane + 1) * (H * W)];

    const float s1 = wave_reduce_sum(v0 * v0 + v1 * v1);
    const float n1 = fmaxf(sqrtf(s1), 1e-12f);
    v0 /= n1; v1 /= n1;

    const float s2 = wave_reduce_sum(v0 * v0 + v1 * v1);
    const float n2 = fmaxf(sqrtf(s2), 1e-8f);

    float2 o = make_float2(v0 / n2, v1 / n2);
    *(float2*)(f + (size_t)i * 128 + 2 * lane) = o;
}

// ---------------------------------------------------------------------------
// Kernel 2: per-row loss_i = logsumexp_j(sim[i,j]) - sim[i, label_i].
// One block per row i, 256 threads (4 waves); thread t owns columns t, t+256.
// Shuffle reductions + single 4-element cross-wave combine (2 barriers total
// after the fi stage).
// ---------------------------------------------------------------------------
__global__ __launch_bounds__(256) void row_loss_kernel(
        const float* __restrict__ f,
        const int* __restrict__ slab,
        const int* __restrict__ dlab,
        const int* __restrict__ ns_ptr,
        float* __restrict__ row_loss) {
    const int i = blockIdx.x;
    const int t = threadIdx.x;
    const int wave = t >> 6, lane = t & 63;
    const int Ns = ns_ptr[0];

    __shared__ float fi[128];
    __shared__ float sh_slabel;
    __shared__ float wred[4];
    if (t < 128) fi[t] = f[(size_t)i * 128 + t];
    __syncthreads();

    const int label = (i < Ns) ? slab[i] : dlab[i - Ns];
    const float4* fi4 = (const float4*)fi;

    float sv[2];
    #pragma unroll
    for (int k = 0; k < 2; ++k) {
        const int j = t + 256 * k;
        if (j < N) {
            const float4* fj = (const float4*)(f + (size_t)j * 128);
            float acc = 0.f;
            #pragma unroll
            for (int c = 0; c < 32; ++c) {
                const float4 a = fi4[c];
                const float4 b = fj[c];
                acc += a.x * b.x + a.y * b.y + a.z * b.z + a.w * b.w;
            }
            acc *= INV_TEMP;
            if (j == label) sh_slabel = acc;  // exactly one writer per block
            sv[k] = acc;
        } else {
            sv[k] = -1e30f;
        }
    }

    // block max: wave shuffle reduce -> 4-wide LDS combine
    float wm = wave_reduce_max(fmaxf(sv[0], sv[1]));
    if (lane == 0) wred[wave] = wm;
    __syncthreads();
    const float mx = fmaxf(fmaxf(wred[0], wred[1]), fmaxf(wred[2], wred[3]));

    float e = 0.f;
    if (t < N)       e += expf(sv[0] - mx);
    if (t + 256 < N) e += expf(sv[1] - mx);
    float ws = wave_reduce_sum(e);
    __syncthreads();  // protect wred reuse
    if (lane == 0) wred[wave] = ws;
    __syncthreads();

    if (t == 0) {
        const float tot = (wred[0] + wred[1]) + (wred[2] + wred[3]);
        const float lse = mx + logf(tot);
        row_loss[i] = lse - sh_slabel;
    }
}

// ---------------------------------------------------------------------------
// Kernel 3: deterministic final reduce of 500 row losses -> scalar loss.
// ---------------------------------------------------------------------------
__global__ __launch_bounds__(256) void final_reduce_kernel(
        const float* __restrict__ row_loss,
        float* __restrict__ out) {
    const int t = threadIdx.x;
    const int lane = t & 63, wave = t >> 6;
    float a = 0.f;
    for (int j = t; j < N; j += 256) a += row_loss[j];
    float ws = wave_reduce_sum(a);
    __shared__ float wred[4];
    if (lane == 0) wred[wave] = ws;
    __syncthreads();
    if (t == 0) {
        const float tot = (wred[0] + wred[1]) + (wred[2] + wred[3]);
        out[0] = tot * (LOSS_SCALE / (float)N);
    }
}

extern "C" void kernel_launch(void* const* d_in, const int* in_sizes, int n_in,
                              void* d_out, int out_size, void* d_ws, size_t ws_size,
                              hipStream_t stream) {
    const float* sf   = (const float*)d_in[0];  // (4,128,512,512) f32
    const float* gt   = (const float*)d_in[1];  // (4,500,8) f32
    const int*   slab = (const int*)d_in[2];    // (250,) i32
    const int*   dlab = (const int*)d_in[3];    // (250,) i32
    const int*   nsp  = (const int*)d_in[4];    // scalar 250

    float* f        = (float*)d_ws;             // N*128 floats = 256 KB
    float* row_loss = f + (size_t)N * 128;      // N floats

    gather_norm_kernel<<<125, 256, 0, stream>>>(sf, gt, f);
    row_loss_kernel<<<N, 256, 0, stream>>>(f, slab, dlab, nsp, row_loss);
    final_reduce_kernel<<<1, 256, 0, stream>>>(row_loss, (float*)d_out);
}